// Round 3
// baseline (1161.303 us; speedup 1.0000x reference)
//
#include <hip/hip_runtime.h>
#include <hip/hip_bf16.h>

#define NE 8
#define HD 256
#define NT 128
#define NTHREADS 512

typedef __attribute__((ext_vector_type(8))) short short8;
typedef __attribute__((ext_vector_type(4))) float f32x4;

__device__ __forceinline__ unsigned short f2bf(float f) {
    union { float f; unsigned int u; } v; v.f = f;
    return (unsigned short)((v.u + 0x7FFFu + ((v.u >> 16) & 1u)) >> 16);
}
__device__ __forceinline__ float bf2f(unsigned short s) {
    union { unsigned int u; float f; } v; v.u = ((unsigned int)s) << 16;
    return v.f;
}
// XOR-swizzled LDS index (element units); keeps 8-element (16B) chunks aligned,
// and preserves 4-element (8B) groups since the XOR operand is a multiple of 8.
__device__ __forceinline__ int swz(int row, int col) {
    return row * HD + (col ^ ((row & 7) << 3));
}

// One-time prep: W[e][k][n] fp32 -> Wt[e][n][k] bf16 (contiguous-K A-fragments).
__global__ void prep_weights(const float* __restrict__ W1, const float* __restrict__ W2,
                             unsigned short* __restrict__ W1t, unsigned short* __restrict__ W2t) {
    int idx = blockIdx.x * blockDim.x + threadIdx.x;
    if (idx >= NE * HD * HD) return;
    int nn = idx & 255;          // coalesced read dim
    int kk = (idx >> 8) & 255;
    int e  = idx >> 16;
    W1t[(e * HD + nn) * HD + kk] = f2bf(W1[(e * HD + kk) * HD + nn]);
    W2t[(e * HD + nn) * HD + kk] = f2bf(W2[(e * HD + kk) * HD + nn]);
}

// One 256x256 layer, operand-swapped: D[neuron][point] = W * Act^T, in-place.
// Act: LDS [point][neuron] bf16 row-major, XOR-swizzled. Wt: global bf16 [n][k].
// Wave grid: 2 (M=neurons) x 4 (N=points). Wave tile: 128 neurons x 32 points.
__device__ __forceinline__ void gemm_relu_layer(
    unsigned short* Act, const unsigned short* __restrict__ Wt,
    const float* __restrict__ bias, int wm, int wn, int l15, int kg)
{
    f32x4 acc[8][2];
    #pragma unroll
    for (int mt = 0; mt < 8; ++mt) {
        acc[mt][0] = (f32x4){0.f, 0.f, 0.f, 0.f};
        acc[mt][1] = (f32x4){0.f, 0.f, 0.f, 0.f};
    }
    const int pA = wn * 32 + l15;        // nt=0 point
    const int pB = pA + 16;              // nt=1 point
    const unsigned short* WtRow = Wt + (wm * 128 + l15) * HD;

    #pragma unroll
    for (int ks = 0; ks < 8; ++ks) {     // K = 256 in steps of 32
        const int k0 = ks * 32 + kg * 8;
        // B-fragments (activations): 2 ds_read_b128, reused across all 8 mt.
        short8 bf0 = *(const short8*)(Act + swz(pA, k0));
        short8 bf1 = *(const short8*)(Act + swz(pB, k0));
        #pragma unroll
        for (int mt = 0; mt < 8; ++mt) {
            // A-fragment (weights): 16B contiguous, L1/L2-resident.
            short8 af = *(const short8*)(WtRow + mt * 16 * HD + k0);
            acc[mt][0] = __builtin_amdgcn_mfma_f32_16x16x32_bf16(af, bf0, acc[mt][0], 0, 0, 0);
            acc[mt][1] = __builtin_amdgcn_mfma_f32_16x16x32_bf16(af, bf1, acc[mt][1], 0, 0, 0);
        }
    }
    __syncthreads();   // all reads of Act done -> safe to overwrite in place
    // Epilogue: D layout col(point)=lane&15, row(neuron)=kg*4+r -> lane holds
    // 4 CONSECUTIVE neurons for one point -> packed 8B ds_write_b64.
    #pragma unroll
    for (int mt = 0; mt < 8; ++mt) {
        const int n0 = wm * 128 + mt * 16 + kg * 4;
        const f32x4 bb = *(const f32x4*)(bias + n0);
        #pragma unroll
        for (int nt = 0; nt < 2; ++nt) {
            const int p = wn * 32 + nt * 16 + l15;
            unsigned int lo = (unsigned int)f2bf(fmaxf(acc[mt][nt][0] + bb[0], 0.f))
                            | ((unsigned int)f2bf(fmaxf(acc[mt][nt][1] + bb[1], 0.f)) << 16);
            unsigned int hi = (unsigned int)f2bf(fmaxf(acc[mt][nt][2] + bb[2], 0.f))
                            | ((unsigned int)f2bf(fmaxf(acc[mt][nt][3] + bb[3], 0.f)) << 16);
            *(uint2*)(Act + swz(p, n0)) = make_uint2(lo, hi);
        }
    }
    __syncthreads();   // writes visible before next layer reads
}

__global__ __launch_bounds__(NTHREADS, 2) void moe_fused(
    const float* __restrict__ coords, int npts,
    const float* __restrict__ W0, const float* __restrict__ b0,
    const unsigned short* __restrict__ W1t, const float* __restrict__ b1,
    const unsigned short* __restrict__ W2t, const float* __restrict__ b2,
    const float* __restrict__ W3, const float* __restrict__ b3,
    float* __restrict__ out)
{
    __shared__ __align__(16) unsigned short Act[NT * HD];  // 64 KB, single buffer
    __shared__ float cbuf[NT * 3];

    const int t = threadIdx.x;
    const int lane = t & 63;
    const int w = t >> 6;
    const int l15 = lane & 15;
    const int kg = lane >> 4;
    const int wm = w >> 2;     // 0..1  (neuron half)
    const int wn = w & 3;      // 0..3  (point quarter)
    const int p0 = blockIdx.x * NT;

    if (t < NT * 3) {
        int idx = p0 * 3 + t;
        int lim = npts * 3 - 1;
        cbuf[t] = coords[idx < lim ? idx : lim];   // clamp: in-bounds, tail masked on store
    }

    // layer-0 mapping: thread owns 2 consecutive neurons x 32 points
    const int j2 = (t & 127) * 2;
    const int prow0 = (t >> 7) * 32;
    // layer-3 mapping: point = w*16 + l15, k-quarter = kg*64
    const int p3 = w * 16 + l15;

    float runmax = -3.4e38f;

    for (int e = 0; e < NE; ++e) {
        __syncthreads();   // Act free (prev expert layer3 done / first iter)
        // ---- layer 0: 3 -> 256, fp32 VALU, packed b32 writes ----
        {
            const float wx0 = W0[(e*3+0)*HD + j2], wx1 = W0[(e*3+0)*HD + j2+1];
            const float wy0 = W0[(e*3+1)*HD + j2], wy1 = W0[(e*3+1)*HD + j2+1];
            const float wz0 = W0[(e*3+2)*HD + j2], wz1 = W0[(e*3+2)*HD + j2+1];
            const float bb0 = b0[e*HD + j2],       bb1 = b0[e*HD + j2+1];
            #pragma unroll 4
            for (int pp = 0; pp < 32; ++pp) {
                int p = prow0 + pp;
                float x = cbuf[p*3], y = cbuf[p*3+1], z = cbuf[p*3+2];
                float h0 = fmaxf(x*wx0 + y*wy0 + z*wz0 + bb0, 0.f);
                float h1 = fmaxf(x*wx1 + y*wy1 + z*wz1 + bb1, 0.f);
                unsigned int pk = (unsigned int)f2bf(h0) | ((unsigned int)f2bf(h1) << 16);
                *(unsigned int*)(Act + swz(p, j2)) = pk;
            }
        }
        __syncthreads();
        // ---- layers 1,2: in-place operand-swapped GEMMs ----
        gemm_relu_layer(Act, W1t + e*HD*HD, b1 + e*HD, wm, wn, l15, kg);
        gemm_relu_layer(Act, W2t + e*HD*HD, b2 + e*HD, wm, wn, l15, kg);
        // ---- layer 3: 256 -> 1; 4 lanes/point (kg = k-quarter), conflict-free ----
        {
            const float* w3 = W3 + e * HD;
            float s = 0.f;
            #pragma unroll
            for (int c = 0; c < 8; ++c) {
                int k = kg * 64 + c * 8;
                short8 hv = *(const short8*)(Act + swz(p3, k));
                const float* w3k = w3 + k;
                #pragma unroll
                for (int j = 0; j < 8; ++j)
                    s += bf2f((unsigned short)hv[j]) * w3k[j];
            }
            s += __shfl_xor(s, 16);
            s += __shfl_xor(s, 32);
            runmax = fmaxf(runmax, s + b3[e]);
        }
    }
    if (kg == 0) {
        int p = p0 + p3;
        if (p < npts) out[p] = runmax;
    }
}

extern "C" void kernel_launch(void* const* d_in, const int* in_sizes, int n_in,
                              void* d_out, int out_size, void* d_ws, size_t ws_size,
                              hipStream_t stream) {
    const float* coords = (const float*)d_in[0];
    const float* W0 = (const float*)d_in[1];
    const float* b0 = (const float*)d_in[2];
    const float* W1 = (const float*)d_in[3];
    const float* b1 = (const float*)d_in[4];
    const float* W2 = (const float*)d_in[5];
    const float* b2 = (const float*)d_in[6];
    const float* W3 = (const float*)d_in[7];
    const float* b3 = (const float*)d_in[8];
    const int npts = in_sizes[0] / 3;

    unsigned short* W1t = (unsigned short*)d_ws;               // 1 MB
    unsigned short* W2t = W1t + NE * HD * HD;                  // 1 MB

    prep_weights<<<(NE * HD * HD + 255) / 256, 256, 0, stream>>>(W1, W2, W1t, W2t);

    int nblocks = (npts + NT - 1) / NT;
    moe_fused<<<nblocks, NTHREADS, 0, stream>>>(
        coords, npts, W0, b0, W1t, b1, W2t, b2, W3, b3, (float*)d_out);
}

// Round 5
// 502.426 us; speedup vs baseline: 2.3114x; 2.3114x over previous
//
#include <hip/hip_runtime.h>
#include <hip/hip_bf16.h>

#define NE 8
#define HD 256
#define NT 128
#define NTHREADS 512

typedef __attribute__((ext_vector_type(8))) short short8;
typedef __attribute__((ext_vector_type(4))) float f32x4;

__device__ __forceinline__ unsigned short f2bf(float f) {
    union { float f; unsigned int u; } v; v.f = f;
    return (unsigned short)((v.u + 0x7FFFu + ((v.u >> 16) & 1u)) >> 16);
}
__device__ __forceinline__ float bf2f(unsigned short s) {
    union { unsigned int u; float f; } v; v.u = ((unsigned int)s) << 16;
    return v.f;
}
// XOR-swizzled LDS index (element units); keeps 8-element (16B) chunks aligned,
// and preserves 4-element (8B) groups since the XOR operand is a multiple of 8.
__device__ __forceinline__ int swz(int row, int col) {
    return row * HD + (col ^ ((row & 7) << 3));
}

// One-time prep: W[e][k][n] fp32 -> Wt[e][n][k] bf16 (contiguous-K A-fragments).
__global__ void prep_weights(const float* __restrict__ W1, const float* __restrict__ W2,
                             unsigned short* __restrict__ W1t, unsigned short* __restrict__ W2t) {
    int idx = blockIdx.x * blockDim.x + threadIdx.x;
    if (idx >= NE * HD * HD) return;
    int nn = idx & 255;          // coalesced read dim
    int kk = (idx >> 8) & 255;
    int e  = idx >> 16;
    W1t[(e * HD + nn) * HD + kk] = f2bf(W1[(e * HD + kk) * HD + nn]);
    W2t[(e * HD + nn) * HD + kk] = f2bf(W2[(e * HD + kk) * HD + nn]);
}

// One 256x256 layer, swapped MFMA: D[neuron][point] = W * Act^T, in-place.
// Wave decomposition: wave w owns neurons [w*32, w*32+32) (A/M dim, L2 loads
// DISJOINT across waves) and iterates ALL 128 points (B/N dim, 8 nt tiles).
// Act: LDS [point][neuron] bf16, XOR-swizzled. Wt: global bf16 [n][k].
__device__ __forceinline__ void gemm_relu_layer(
    unsigned short* Act, const unsigned short* __restrict__ Wt,
    const float* __restrict__ bias, int w, int l15, int kg)
{
    f32x4 acc[2][8];
    #pragma unroll
    for (int mt = 0; mt < 2; ++mt)
        #pragma unroll
        for (int nt = 0; nt < 8; ++nt)
            acc[mt][nt] = (f32x4){0.f, 0.f, 0.f, 0.f};

    const unsigned short* Wt0 = Wt + (w * 32 + l15) * HD;       // mt=0 row
    const unsigned short* Wt1 = Wt0 + 16 * HD;                  // mt=1 row

    #pragma unroll
    for (int ks = 0; ks < 8; ++ks) {     // K = 256 in steps of 32
        const int k0 = ks * 32 + kg * 8;
        // A-fragments (weights): 2x 16B from L2, disjoint across waves.
        short8 af0 = *(const short8*)(Wt0 + k0);
        short8 af1 = *(const short8*)(Wt1 + k0);
        #pragma unroll
        for (int nt = 0; nt < 8; ++nt) {
            // B-fragment (activations): ds_read_b128, reused by 2 MFMAs.
            short8 bf = *(const short8*)(Act + swz(nt * 16 + l15, k0));
            acc[0][nt] = __builtin_amdgcn_mfma_f32_16x16x32_bf16(af0, bf, acc[0][nt], 0, 0, 0);
            acc[1][nt] = __builtin_amdgcn_mfma_f32_16x16x32_bf16(af1, bf, acc[1][nt], 0, 0, 0);
        }
    }
    __syncthreads();   // all reads of Act done -> safe to overwrite in place
    // Epilogue: D layout col(point)=lane&15, row(neuron)=kg*4+r -> lane holds
    // 4 CONSECUTIVE neurons for one point -> packed 8B ds_write_b64.
    #pragma unroll
    for (int mt = 0; mt < 2; ++mt) {
        const int n0 = w * 32 + mt * 16 + kg * 4;
        const f32x4 bb = *(const f32x4*)(bias + n0);
        #pragma unroll
        for (int nt = 0; nt < 8; ++nt) {
            const int p = nt * 16 + l15;
            unsigned int lo = (unsigned int)f2bf(fmaxf(acc[mt][nt][0] + bb[0], 0.f))
                            | ((unsigned int)f2bf(fmaxf(acc[mt][nt][1] + bb[1], 0.f)) << 16);
            unsigned int hi = (unsigned int)f2bf(fmaxf(acc[mt][nt][2] + bb[2], 0.f))
                            | ((unsigned int)f2bf(fmaxf(acc[mt][nt][3] + bb[3], 0.f)) << 16);
            *(uint2*)(Act + swz(p, n0)) = make_uint2(lo, hi);
        }
    }
    __syncthreads();   // writes visible before next layer reads
}

__global__ __launch_bounds__(NTHREADS, 2) void moe_fused(
    const float* __restrict__ coords, int npts,
    const float* __restrict__ W0, const float* __restrict__ b0,
    const unsigned short* __restrict__ W1t, const float* __restrict__ b1,
    const unsigned short* __restrict__ W2t, const float* __restrict__ b2,
    const float* __restrict__ W3, const float* __restrict__ b3,
    float* __restrict__ out)
{
    __shared__ __align__(16) unsigned short Act[NT * HD];  // 64 KB, single buffer
    __shared__ float cbuf[NT * 3];

    const int t = threadIdx.x;
    const int lane = t & 63;
    const int w = t >> 6;
    const int l15 = lane & 15;
    const int kg = lane >> 4;
    const int p0 = blockIdx.x * NT;

    if (t < NT * 3) {
        int idx = p0 * 3 + t;
        int lim = npts * 3 - 1;
        cbuf[t] = coords[idx < lim ? idx : lim];   // clamp: in-bounds, tail masked on store
    }

    // layer-0 mapping: thread owns 2 consecutive neurons x 32 points
    const int j2 = (t & 127) * 2;
    const int prow0 = (t >> 7) * 32;
    // layer-3 mapping: point = w*16 + l15, k-quarter = kg*64
    const int p3 = w * 16 + l15;

    float runmax = -3.4e38f;

    for (int e = 0; e < NE; ++e) {
        __syncthreads();   // Act free (prev expert layer3 done / first iter)
        // ---- layer 0: 3 -> 256, fp32 VALU, packed b32 writes ----
        {
            const float wx0 = W0[(e*3+0)*HD + j2], wx1 = W0[(e*3+0)*HD + j2+1];
            const float wy0 = W0[(e*3+1)*HD + j2], wy1 = W0[(e*3+1)*HD + j2+1];
            const float wz0 = W0[(e*3+2)*HD + j2], wz1 = W0[(e*3+2)*HD + j2+1];
            const float bb0 = b0[e*HD + j2],       bb1 = b0[e*HD + j2+1];
            #pragma unroll 4
            for (int pp = 0; pp < 32; ++pp) {
                int p = prow0 + pp;
                float x = cbuf[p*3], y = cbuf[p*3+1], z = cbuf[p*3+2];
                float h0 = fmaxf(x*wx0 + y*wy0 + z*wz0 + bb0, 0.f);
                float h1 = fmaxf(x*wx1 + y*wy1 + z*wz1 + bb1, 0.f);
                unsigned int pk = (unsigned int)f2bf(h0) | ((unsigned int)f2bf(h1) << 16);
                *(unsigned int*)(Act + swz(p, j2)) = pk;
            }
        }
        __syncthreads();
        // ---- layers 1,2: in-place swapped GEMMs, neuron-partitioned waves ----
        gemm_relu_layer(Act, W1t + e*HD*HD, b1 + e*HD, w, l15, kg);
        gemm_relu_layer(Act, W2t + e*HD*HD, b2 + e*HD, w, l15, kg);
        // ---- layer 3: 256 -> 1; 4 lanes/point (kg = k-quarter) ----
        {
            const float* w3 = W3 + e * HD;
            float s = 0.f;
            #pragma unroll
            for (int c = 0; c < 8; ++c) {
                int k = kg * 64 + c * 8;
                short8 hv = *(const short8*)(Act + swz(p3, k));
                const float* w3k = w3 + k;
                #pragma unroll
                for (int j = 0; j < 8; ++j)
                    s += bf2f((unsigned short)hv[j]) * w3k[j];
            }
            s += __shfl_xor(s, 16);
            s += __shfl_xor(s, 32);
            runmax = fmaxf(runmax, s + b3[e]);
        }
    }
    if (kg == 0) {
        int p = p0 + p3;
        if (p < npts) out[p] = runmax;
    }
}

extern "C" void kernel_launch(void* const* d_in, const int* in_sizes, int n_in,
                              void* d_out, int out_size, void* d_ws, size_t ws_size,
                              hipStream_t stream) {
    const float* coords = (const float*)d_in[0];
    const float* W0 = (const float*)d_in[1];
    const float* b0 = (const float*)d_in[2];
    const float* W1 = (const float*)d_in[3];
    const float* b1 = (const float*)d_in[4];
    const float* W2 = (const float*)d_in[5];
    const float* b2 = (const float*)d_in[6];
    const float* W3 = (const float*)d_in[7];
    const float* b3 = (const float*)d_in[8];
    const int npts = in_sizes[0] / 3;

    unsigned short* W1t = (unsigned short*)d_ws;               // 1 MB
    unsigned short* W2t = W1t + NE * HD * HD;                  // 1 MB

    prep_weights<<<(NE * HD * HD + 255) / 256, 256, 0, stream>>>(W1, W2, W1t, W2t);

    int nblocks = (npts + NT - 1) / NT;
    moe_fused<<<nblocks, NTHREADS, 0, stream>>>(
        coords, npts, W0, b0, W1t, b1, W2t, b2, W3, b3, (float*)d_out);
}

// Round 6
// 493.347 us; speedup vs baseline: 2.3539x; 1.0184x over previous
//
#include <hip/hip_runtime.h>
#include <hip/hip_bf16.h>

#define NE 8
#define HD 256
#define NT 64
#define NTHREADS 512

typedef __attribute__((ext_vector_type(8))) short short8;
typedef __attribute__((ext_vector_type(4))) float f32x4;

__device__ __forceinline__ unsigned short f2bf(float f) {
    union { float f; unsigned int u; } v; v.f = f;
    return (unsigned short)((v.u + 0x7FFFu + ((v.u >> 16) & 1u)) >> 16);
}
// XOR-swizzled LDS index (element units); keeps 16B chunks aligned and 4-elem
// (8B) groups intact since the XOR operand is a multiple of 8.
__device__ __forceinline__ int swz(int row, int col) {
    return row * HD + (col ^ ((row & 7) << 3));
}

// One-time prep: W[e][k][n] fp32 -> Wt[e][n][k] bf16 (contiguous-K A-fragments).
__global__ void prep_weights(const float* __restrict__ W1, const float* __restrict__ W2,
                             unsigned short* __restrict__ W1t, unsigned short* __restrict__ W2t) {
    int idx = blockIdx.x * blockDim.x + threadIdx.x;
    if (idx >= NE * HD * HD) return;
    int nn = idx & 255;          // coalesced read dim
    int kk = (idx >> 8) & 255;
    int e  = idx >> 16;
    W1t[(e * HD + nn) * HD + kk] = f2bf(W1[(e * HD + kk) * HD + nn]);
    W2t[(e * HD + nn) * HD + kk] = f2bf(W2[(e * HD + kk) * HD + nn]);
}

// K-loop only: acc[mt][nt] += W * Act^T for this wave's 32 neurons x 64 points.
__device__ __forceinline__ void gemm_kloop(
    const unsigned short* Act, const unsigned short* __restrict__ Wt,
    int w, int l15, int kg, f32x4 acc[2][4])
{
    #pragma unroll
    for (int mt = 0; mt < 2; ++mt)
        #pragma unroll
        for (int nt = 0; nt < 4; ++nt)
            acc[mt][nt] = (f32x4){0.f, 0.f, 0.f, 0.f};

    const unsigned short* Wt0 = Wt + (w * 32 + l15) * HD;   // mt=0 row
    const unsigned short* Wt1 = Wt0 + 16 * HD;              // mt=1 row

    #pragma unroll
    for (int ks = 0; ks < 8; ++ks) {     // K = 256 in steps of 32
        const int k0 = ks * 32 + kg * 8;
        short8 af0 = *(const short8*)(Wt0 + k0);            // L2-resident, disjoint/wave
        short8 af1 = *(const short8*)(Wt1 + k0);
        #pragma unroll
        for (int nt = 0; nt < 4; ++nt) {
            short8 bf = *(const short8*)(Act + swz(nt * 16 + l15, k0)); // ds_read_b128
            acc[0][nt] = __builtin_amdgcn_mfma_f32_16x16x32_bf16(af0, bf, acc[0][nt], 0, 0, 0);
            acc[1][nt] = __builtin_amdgcn_mfma_f32_16x16x32_bf16(af1, bf, acc[1][nt], 0, 0, 0);
        }
    }
}

__global__ __launch_bounds__(NTHREADS, 4) void moe_fused(
    const float* __restrict__ coords, int npts,
    const float* __restrict__ W0, const float* __restrict__ b0,
    const unsigned short* __restrict__ W1t, const float* __restrict__ b1,
    const unsigned short* __restrict__ W2t, const float* __restrict__ b2,
    const float* __restrict__ W3, const float* __restrict__ b3,
    float* __restrict__ out)
{
    __shared__ __align__(16) unsigned short Act[NT * HD];   // 32 KB
    __shared__ float cbuf[NT * 3];                          // 768 B
    __shared__ float pscr[NT * 8];                          // 2 KB

    const int t = threadIdx.x;
    const int lane = t & 63;
    const int w = t >> 6;
    const int l15 = lane & 15;
    const int kg = lane >> 4;
    const int p0 = blockIdx.x * NT;

    if (t < NT * 3) {
        int idx = p0 * 3 + t;
        int lim = npts * 3 - 1;
        cbuf[t] = coords[idx < lim ? idx : lim];   // clamp: in-bounds, tail masked on store
    }

    // layer-0 mapping: thread owns 2 consecutive neurons x 16 points
    const int j2 = (t & 127) * 2;
    const int prow0 = (t >> 7) * 16;

    float runmax = -3.4e38f;
    f32x4 acc[2][4];

    for (int e = 0; e < NE; ++e) {
        __syncthreads();   // cbuf ready / Act & pscr free from previous expert
        // ---- layer 0: 3 -> 256, fp32 VALU, packed b32 writes ----
        {
            const float wx0 = W0[(e*3+0)*HD + j2], wx1 = W0[(e*3+0)*HD + j2+1];
            const float wy0 = W0[(e*3+1)*HD + j2], wy1 = W0[(e*3+1)*HD + j2+1];
            const float wz0 = W0[(e*3+2)*HD + j2], wz1 = W0[(e*3+2)*HD + j2+1];
            const float bb0 = b0[e*HD + j2],       bb1 = b0[e*HD + j2+1];
            #pragma unroll 4
            for (int pp = 0; pp < 16; ++pp) {
                int p = prow0 + pp;
                float x = cbuf[p*3], y = cbuf[p*3+1], z = cbuf[p*3+2];
                float h0 = fmaxf(x*wx0 + y*wy0 + z*wz0 + bb0, 0.f);
                float h1 = fmaxf(x*wx1 + y*wy1 + z*wz1 + bb1, 0.f);
                unsigned int pk = (unsigned int)f2bf(h0) | ((unsigned int)f2bf(h1) << 16);
                *(unsigned int*)(Act + swz(p, j2)) = pk;
            }
        }
        __syncthreads();
        // ---- layer 1 K-loop ----
        gemm_kloop(Act, W1t + e*HD*HD, w, l15, kg, acc);
        __syncthreads();   // all reads done -> overwrite Act in place
        // ---- layer 1 epilogue: bias+relu, packed 8B writes ----
        #pragma unroll
        for (int mt = 0; mt < 2; ++mt) {
            const int n0 = w * 32 + mt * 16 + kg * 4;
            const f32x4 bb = *(const f32x4*)(b1 + e*HD + n0);
            #pragma unroll
            for (int nt = 0; nt < 4; ++nt) {
                const int p = nt * 16 + l15;
                unsigned int lo = (unsigned int)f2bf(fmaxf(acc[mt][nt][0] + bb[0], 0.f))
                                | ((unsigned int)f2bf(fmaxf(acc[mt][nt][1] + bb[1], 0.f)) << 16);
                unsigned int hi = (unsigned int)f2bf(fmaxf(acc[mt][nt][2] + bb[2], 0.f))
                                | ((unsigned int)f2bf(fmaxf(acc[mt][nt][3] + bb[3], 0.f)) << 16);
                *(uint2*)(Act + swz(p, n0)) = make_uint2(lo, hi);
            }
        }
        __syncthreads();
        // ---- layer 2 K-loop ----
        gemm_kloop(Act, W2t + e*HD*HD, w, l15, kg, acc);
        // ---- fused layer-2 epilogue + layer 3 (all in registers, fp32) ----
        {
            const int n0 = w * 32 + kg * 4;
            const f32x4 bb0 = *(const f32x4*)(b2 + e*HD + n0);
            const f32x4 bb1 = *(const f32x4*)(b2 + e*HD + n0 + 16);
            const f32x4 w30 = *(const f32x4*)(W3 + e*HD + n0);
            const f32x4 w31 = *(const f32x4*)(W3 + e*HD + n0 + 16);
            #pragma unroll
            for (int nt = 0; nt < 4; ++nt) {
                float s = 0.f;
                #pragma unroll
                for (int r = 0; r < 4; ++r) {
                    s += fmaxf(acc[0][nt][r] + bb0[r], 0.f) * w30[r];
                    s += fmaxf(acc[1][nt][r] + bb1[r], 0.f) * w31[r];
                }
                s += __shfl_xor(s, 16);   // reduce over kg (4 lanes per point)
                s += __shfl_xor(s, 32);
                if (kg == 0) pscr[(nt * 16 + l15) * 8 + w] = s;  // per-wave partial
            }
        }
        __syncthreads();   // pscr ready; Act reads all done (next L0 may overwrite)
        if (t < NT) {
            float s = 0.f;
            #pragma unroll
            for (int j = 0; j < 8; ++j) s += pscr[t * 8 + j];
            runmax = fmaxf(runmax, s + b3[e]);
        }
    }
    if (t < NT) {
        int p = p0 + t;
        if (p < npts) out[p] = runmax;
    }
}

extern "C" void kernel_launch(void* const* d_in, const int* in_sizes, int n_in,
                              void* d_out, int out_size, void* d_ws, size_t ws_size,
                              hipStream_t stream) {
    const float* coords = (const float*)d_in[0];
    const float* W0 = (const float*)d_in[1];
    const float* b0 = (const float*)d_in[2];
    const float* W1 = (const float*)d_in[3];
    const float* b1 = (const float*)d_in[4];
    const float* W2 = (const float*)d_in[5];
    const float* b2 = (const float*)d_in[6];
    const float* W3 = (const float*)d_in[7];
    const float* b3 = (const float*)d_in[8];
    const int npts = in_sizes[0] / 3;

    unsigned short* W1t = (unsigned short*)d_ws;               // 1 MB
    unsigned short* W2t = W1t + NE * HD * HD;                  // 1 MB

    prep_weights<<<(NE * HD * HD + 255) / 256, 256, 0, stream>>>(W1, W2, W1t, W2t);

    int nblocks = (npts + NT - 1) / NT;
    moe_fused<<<nblocks, NTHREADS, 0, stream>>>(
        coords, npts, W0, b0, W1t, b1, W2t, b2, W3, b3, (float*)d_out);
}